// Round 10
// baseline (960.166 us; speedup 1.0000x reference)
//
#include <hip/hip_runtime.h>
#include <hip/hip_bf16.h>
#include <hip/hip_fp16.h>

#define N_NODES 100000
#define E_EDGES 1600000
#define FDIM 128
#define NGRAPH 256
#define NPB 256            // nodes per bucket (dst >> 8)
#define NBUCKET 391        // ceil(N / 256)
#define SLAB 4800          // slab capacity (mean 4092, sigma ~64, +11 sigma)
#define BCHUNK 2048        // edges per bin block (small => parallelism)
#define NBINBLK ((E_EDGES + BCHUNK - 1) / BCHUNK)   // 782
#define LDSW 136           // padded bf16 row stride (128 + 8)
#define SREP 16            // stats replication
#define NSHARD 8           // channel shards (== XCD count)

typedef __attribute__((ext_vector_type(8))) short bf16x8;
typedef __attribute__((ext_vector_type(4))) float f32x4;

__device__ __forceinline__ unsigned pack_bf16(float a, float b) {
    unsigned ua = __float_as_uint(a);
    unsigned ub = __float_as_uint(b);
    ua = ua + 0x7fffu + ((ua >> 16) & 1u);
    ub = ub + 0x7fffu + ((ub >> 16) & 1u);
    return (ua >> 16) | (ub & 0xffff0000u);
}
__device__ __forceinline__ unsigned short bf16_1(float a) {
    unsigned ua = __float_as_uint(a);
    ua = ua + 0x7fffu + ((ua >> 16) & 1u);
    return (unsigned short)(ua >> 16);
}
__device__ __forceinline__ float bf_lo(unsigned u) { return __uint_as_float(u << 16); }
__device__ __forceinline__ float bf_hi(unsigned u) { return __uint_as_float(u & 0xffff0000u); }

// ---------------- preprocessing ----------------

__global__ void initk(float* __restrict__ statsP, float* __restrict__ sums,
                      int* __restrict__ cursor) {
    int i = blockIdx.x * blockDim.x + threadIdx.x;
    if (i < 3 * SREP * 256) statsP[i] = 0.0f;       // replicated stats slabs
    if (i < NGRAPH * FDIM) sums[i] = 0.0f;          // pooled sums
    if (i < NBUCKET) cursor[i] = i * SLAB;          // bucket slab cursors
}

// Phase 1: bin edges by dst bucket; clustered slab writes.
__global__ __launch_bounds__(256) void bink(const int* __restrict__ ei,
                                            int* __restrict__ cursor,
                                            int* __restrict__ bcsr) {
    __shared__ int hist[NBUCKET];
    __shared__ int base[NBUCKET];
    int t = threadIdx.x;
    for (int b = t; b < NBUCKET; b += 256) hist[b] = 0;
    __syncthreads();
    int e0 = blockIdx.x * BCHUNK;
    int e1 = e0 + BCHUNK; if (e1 > E_EDGES) e1 = E_EDGES;
    for (int e = e0 + t; e < e1; e += 256) {
        atomicAdd(&hist[ei[E_EDGES + e] >> 8], 1);
    }
    __syncthreads();
    for (int b = t; b < NBUCKET; b += 256) {
        int h = hist[b];
        base[b] = h ? atomicAdd(&cursor[b], h) : 0;
        hist[b] = 0;
    }
    __syncthreads();
    for (int e = e0 + t; e < e1; e += 256) {
        int s = ei[e];
        int d = ei[E_EDGES + e];
        int bk = d >> 8;
        int lp = atomicAdd(&hist[bk], 1);
        int pos = base[bk] + lp;
        if (pos < (bk + 1) * SLAB)                    // overflow guard
            bcsr[pos] = s | ((d & 255) << 17);
    }
}

// Phase 2: per-bucket LDS counting sort -> per-node grouping (in place, keeps
// dst-local bits), per-node offsets, in-counts, and dinv.
__global__ __launch_bounds__(256) void sortk(const int* __restrict__ cursor,
                                             int* __restrict__ bcsr,
                                             int* __restrict__ offs,
                                             int* __restrict__ inCnt,
                                             float* __restrict__ dinv) {
    __shared__ int ent[SLAB];      // 19.2 KB
    __shared__ int hist[NPB];
    __shared__ int hcur[NPB];
    __shared__ int htmp[NPB];
    int t = threadIdx.x;
    int bk = blockIdx.x;
    int slab = bk * SLAB;
    int cnt = cursor[bk] - slab;
    if (cnt > SLAB) cnt = SLAB;
    hist[t] = 0;
    __syncthreads();
    for (int i = t; i < cnt; i += 256) {
        int v = bcsr[slab + i];
        ent[i] = v;
        atomicAdd(&hist[v >> 17], 1);
    }
    __syncthreads();
    int myc = hist[t];
    htmp[t] = myc;
    __syncthreads();
    for (int st = 1; st < 256; st <<= 1) {
        int x = htmp[t];
        int y = (t >= st) ? htmp[t - st] : 0;
        __syncthreads();
        htmp[t] = x + y;
        __syncthreads();
    }
    int excl = htmp[t] - myc;
    hist[t] = excl;                 // reuse as scatter base
    hcur[t] = 0;
    int gn = bk * NPB + t;
    if (gn < N_NODES) {
        inCnt[gn] = myc;
        offs[gn] = slab + excl;
        dinv[gn] = rsqrtf((float)(1 + myc));   // +1 self-loop
    }
    __syncthreads();
    for (int i = t; i < cnt; i += 256) {
        int v = ent[i];
        int dl = v >> 17;
        int lp = atomicAdd(&hcur[dl], 1);
        bcsr[slab + hist[dl] + lp] = v;        // keep dl bits for coefk
    }
}

// Phase 3: pack to 4B entries: src(17) | fp16(coef)(15, sign always 0).
__global__ __launch_bounds__(256) void coefk(const int* __restrict__ cursor,
                                             const int* __restrict__ bcsr,
                                             const float* __restrict__ dinv,
                                             unsigned* __restrict__ csrp) {
    int bk = blockIdx.x;
    int slab = bk * SLAB;
    int cnt = cursor[bk] - slab;
    if (cnt > SLAB) cnt = SLAB;
    for (int i = threadIdx.x; i < cnt; i += 256) {
        int v = bcsr[slab + i];
        int s = v & 0x1FFFF;
        int d = bk * NPB + (v >> 17);
        float coef = dinv[s] * dinv[d];
        unsigned hb = (unsigned)__half_as_ushort(__float2half(coef));  // sign=0
        csrp[slab + i] = (unsigned)s | (hb << 17);
    }
}

// W^T (bf16) precompute: Wt[widx][n][k] = bf16(W[k][n])
__global__ __launch_bounds__(256) void transposeW(const float* __restrict__ W1,
                                                  const float* __restrict__ W2,
                                                  const float* __restrict__ W3,
                                                  unsigned short* __restrict__ Wt) {
    int b = blockIdx.x;
    int widx = b >> 3;
    int n0 = (b & 7) * 16;
    const float* W = (widx == 0) ? W1 : (widx == 1) ? W2 : W3;
    unsigned short* dst = Wt + widx * 16384;
    int t = threadIdx.x;
    int n = n0 + (t & 15);
#pragma unroll
    for (int i = 0; i < 8; i++) {
        int k = (t >> 4) + i * 16;
        dst[n * 128 + k] = bf16_1(W[k * 128 + n]);
    }
}

// ---------------- MFMA GEMM: T_bf16[N,128] = act(A[N,128]) @ W ----------------
// MODE 0: A fp32, no BN (layer 1). MODE 1: A bf16 (uint-packed), BN+ReLU fused.

template <int MODE>
__global__ __launch_bounds__(256, 2) void gemmMF(const void* __restrict__ Ain,
                                                 const unsigned short* __restrict__ Wt,
                                                 const float* __restrict__ statsP,
                                                 const float* __restrict__ g,
                                                 const float* __restrict__ be,
                                                 unsigned short* __restrict__ outT) {
    __shared__ unsigned short sA[64 * LDSW];
    __shared__ unsigned short sW[128 * LDSW];
    __shared__ float sScale[FDIM], sBias[FDIM];
    int tid = threadIdx.x;
    if (MODE == 1) {
        if (tid < FDIM) {
            float s = 0.f, q = 0.f;
#pragma unroll
            for (int r = 0; r < SREP; r++) {
                s += statsP[r * 256 + tid];
                q += statsP[r * 256 + 128 + tid];
            }
            float mean = s * (1.0f / N_NODES);
            float var = q * (1.0f / N_NODES) - mean * mean;
            float sc = g[tid] * rsqrtf(var + 1e-5f);
            sScale[tid] = sc;
            sBias[tid] = be[tid] - mean * sc;
        }
        __syncthreads();
    }
    int row0 = blockIdx.x * 64;
    {
        const uint4* Wt4 = (const uint4*)Wt;
#pragma unroll
        for (int i = 0; i < 8; i++) {
            int flat = tid + 256 * i;        // 0..2047
            int r = flat >> 4, c8 = flat & 15;
            uint4 v = Wt4[flat];
            *(uint4*)&sW[r * LDSW + c8 * 8] = v;
        }
    }
    if (MODE == 0) {
        const float4* A4 = (const float4*)Ain;
#pragma unroll
        for (int i = 0; i < 8; i++) {
            int flat = tid + 256 * i;        // 0..2047
            int r = flat >> 5, c4 = flat & 31;
            int grow = row0 + r;
            float4 v = make_float4(0.f, 0.f, 0.f, 0.f);
            if (grow < N_NODES) v = A4[grow * 32 + c4];
            uint2 p;
            p.x = pack_bf16(v.x, v.y);
            p.y = pack_bf16(v.z, v.w);
            *(uint2*)&sA[r * LDSW + c4 * 4] = p;
        }
    } else {
        const uint2* A2 = (const uint2*)Ain;
#pragma unroll
        for (int i = 0; i < 8; i++) {
            int flat = tid + 256 * i;        // 0..2047
            int r = flat >> 5, c4 = flat & 31;
            int grow = row0 + r;
            uint2 u = make_uint2(0u, 0u);
            if (grow < N_NODES) u = A2[grow * 32 + c4];
            int ch = c4 * 4;
            float vx = fmaxf(bf_lo(u.x) * sScale[ch + 0] + sBias[ch + 0], 0.f);
            float vy = fmaxf(bf_hi(u.x) * sScale[ch + 1] + sBias[ch + 1], 0.f);
            float vz = fmaxf(bf_lo(u.y) * sScale[ch + 2] + sBias[ch + 2], 0.f);
            float vw = fmaxf(bf_hi(u.y) * sScale[ch + 3] + sBias[ch + 3], 0.f);
            uint2 p;
            p.x = pack_bf16(vx, vy);
            p.y = pack_bf16(vz, vw);
            *(uint2*)&sA[r * LDSW + c4 * 4] = p;
        }
    }
    __syncthreads();

    int lane = tid & 63;
    int w = tid >> 6;         // wave id: cols w*32..w*32+31
    int rbase = lane & 15;
    int kgrp = lane >> 4;     // 0..3
    f32x4 acc[4][2];
#pragma unroll
    for (int mf = 0; mf < 4; mf++)
#pragma unroll
        for (int nf = 0; nf < 2; nf++) acc[mf][nf] = (f32x4){0.f, 0.f, 0.f, 0.f};

#pragma unroll
    for (int kk = 0; kk < 4; kk++) {
        int kb = kk * 32 + kgrp * 8;
        bf16x8 af[4], bfr[2];
#pragma unroll
        for (int mf = 0; mf < 4; mf++)
            af[mf] = *(const bf16x8*)&sA[(mf * 16 + rbase) * LDSW + kb];
#pragma unroll
        for (int nf = 0; nf < 2; nf++)
            bfr[nf] = *(const bf16x8*)&sW[(w * 32 + nf * 16 + rbase) * LDSW + kb];
#pragma unroll
        for (int mf = 0; mf < 4; mf++)
#pragma unroll
            for (int nf = 0; nf < 2; nf++)
                acc[mf][nf] = __builtin_amdgcn_mfma_f32_16x16x32_bf16(
                    af[mf], bfr[nf], acc[mf][nf], 0, 0, 0);
    }
#pragma unroll
    for (int mf = 0; mf < 4; mf++) {
#pragma unroll
        for (int nf = 0; nf < 2; nf++) {
            int col = w * 32 + nf * 16 + rbase;
#pragma unroll
            for (int j = 0; j < 4; j++) {
                int grow = row0 + mf * 16 + kgrp * 4 + j;
                if (grow < N_NODES) {
                    outT[(size_t)grow * FDIM + col] = bf16_1(acc[mf][nf][j]);
                }
            }
        }
    }
}

// ---------------- edge aggregation: XCD-pinned channel shards ----------------
// grid = 3125*8; shard = blockIdx & 7 (round-robin -> one shard per XCD, so the
// 16-channel T16 slice (3.2 MB) stays L2-resident). 4 waves x 8 nodes per block.
// lane: esub = lane>>3 (edge slot), ch = lane&7 (uint within slice).
// 16 edges in flight per iteration; CSR entries 4B, nontemporal.

__global__ __launch_bounds__(256) void agg(const unsigned* __restrict__ t,
                                           const unsigned* __restrict__ csrp,
                                           const int* __restrict__ offs,
                                           const int* __restrict__ inCnt,
                                           const float* __restrict__ dinv,
                                           const float* __restrict__ bias,
                                           unsigned* __restrict__ outH,
                                           float* __restrict__ statsP) {
    int tid = threadIdx.x;
    int lane = tid & 63;
    int wid = tid >> 6;
    int shard = blockIdx.x & (NSHARD - 1);
    int nbase = (blockIdx.x >> 3) * 32;
    int esub = lane >> 3;
    int ch = lane & 7;
    int tb = shard * 8 + ch;                    // uint column in T16 row
    const float2* bias2 = (const float2*)bias;
    float2 b = bias2[tb];
    float s0 = 0.f, s1 = 0.f, q0 = 0.f, q1 = 0.f;
    for (int it = 0; it < 8; it++) {
        int node = __builtin_amdgcn_readfirstlane(nbase + wid * 8 + it);
        float di = dinv[node];
        int start = offs[node];
        int cnt = inCnt[node];
        float a0 = 0.f, a1 = 0.f;
        for (int e = 0; e < cnt; e += 16) {
            int i0 = e + esub;
            int i1 = e + 8 + esub;
            unsigned v0 = (i0 < cnt) ? __builtin_nontemporal_load(&csrp[start + i0]) : 0u;
            unsigned v1 = (i1 < cnt) ? __builtin_nontemporal_load(&csrp[start + i1]) : 0u;
            unsigned u0 = t[(v0 & 0x1FFFF) * 64 + tb];
            unsigned u1 = t[(v1 & 0x1FFFF) * 64 + tb];
            float f0 = __half2float(__ushort_as_half((unsigned short)(v0 >> 17)));
            float f1 = __half2float(__ushort_as_half((unsigned short)(v1 >> 17)));
            a0 += f0 * bf_lo(u0); a1 += f0 * bf_hi(u0);
            a0 += f1 * bf_lo(u1); a1 += f1 * bf_hi(u1);
        }
        // fold the 8 edge-slot groups (preserve ch bits 0..2)
        a0 += __shfl_xor(a0, 8, 64);  a1 += __shfl_xor(a1, 8, 64);
        a0 += __shfl_xor(a0, 16, 64); a1 += __shfl_xor(a1, 16, 64);
        a0 += __shfl_xor(a0, 32, 64); a1 += __shfl_xor(a1, 32, 64);
        // self-loop + bias
        unsigned su = t[node * 64 + tb];
        float cs = di * di;
        a0 += cs * bf_lo(su) + b.x;
        a1 += cs * bf_hi(su) + b.y;
        if (esub == 0) {
            outH[node * 64 + tb] = pack_bf16(a0, a1);
            s0 += a0; q0 += a0 * a0;
            s1 += a1; q1 += a1 * a1;
        }
    }
    // stats: 16 channels per block
    __shared__ float sS[64], sQ[64];
    if (esub == 0) {
        sS[wid * 16 + 2 * ch + 0] = s0; sQ[wid * 16 + 2 * ch + 0] = q0;
        sS[wid * 16 + 2 * ch + 1] = s1; sQ[wid * 16 + 2 * ch + 1] = q1;
    }
    __syncthreads();
    if (tid < 16) {
        float S = sS[tid] + sS[16 + tid] + sS[32 + tid] + sS[48 + tid];
        float Q = sQ[tid] + sQ[16 + tid] + sQ[32 + tid] + sQ[48 + tid];
        int gch = shard * 16 + tid;
        float* p = statsP + ((blockIdx.x >> 3) & (SREP - 1)) * 256;
        atomicAdd(&p[gch], S);
        atomicAdd(&p[128 + gch], Q);
    }
}

// ---------------- pool phase 1: BN3+ReLU + segment-sum (bf16 H) ----------------

__global__ __launch_bounds__(128) void poolsum(const unsigned* __restrict__ h,
                                               const int* __restrict__ batch,
                                               const float* __restrict__ statsP,
                                               const float* __restrict__ g3,
                                               const float* __restrict__ be3,
                                               float* __restrict__ sums) {
    int c = threadIdx.x;
    int base = blockIdx.x * 64;
    float s = 0.f, q = 0.f;
#pragma unroll
    for (int r = 0; r < SREP; r++) {
        s += statsP[r * 256 + c];
        q += statsP[r * 256 + 128 + c];
    }
    float mean = s * (1.0f / N_NODES);
    float var = q * (1.0f / N_NODES) - mean * mean;
    float sc = g3[c] * rsqrtf(var + 1e-5f);
    float bi = be3[c] - mean * sc;
    __shared__ int sb[64];
    if (c < 64) {
        int idx = base + c;
        sb[c] = (idx < N_NODES) ? batch[idx] : -1;
    }
    __syncthreads();
    float acc = 0.f;
    int gcur = sb[0];
    int half = c & 1;
    int cu = c >> 1;
    for (int r = 0; r < 64; r++) {
        int idx = base + r;
        if (idx >= N_NODES) break;
        int gr = sb[r];
        if (gr != gcur) {
            atomicAdd(&sums[gcur * FDIM + c], acc);
            acc = 0.f;
            gcur = gr;
        }
        unsigned u = h[(size_t)idx * 64 + cu];
        float v = half ? bf_hi(u) : bf_lo(u);
        acc += fmaxf(v * sc + bi, 0.f);
    }
    atomicAdd(&sums[gcur * FDIM + c], acc);
}

// ---------------- pool phase 2: divide + final linear ----------------

__global__ __launch_bounds__(128) void finalk(const float* __restrict__ sums,
                                              const int* __restrict__ batch,
                                              const float* __restrict__ Wl,
                                              const float* __restrict__ bl,
                                              float* __restrict__ out) {
    int g = blockIdx.x;
    int c = threadIdx.x;
    int lo = 0, hi = N_NODES;
    while (lo < hi) { int m = (lo + hi) >> 1; if (batch[m] < g) lo = m + 1; else hi = m; }
    int start = lo;
    lo = start; hi = N_NODES;
    while (lo < hi) { int m = (lo + hi) >> 1; if (batch[m] < g + 1) lo = m + 1; else hi = m; }
    int cnt = lo - start;
    float v = sums[g * FDIM + c] / fmaxf((float)cnt, 1.0f) * Wl[c];
    __shared__ float red[FDIM];
    red[c] = v;
    __syncthreads();
    for (int st = 64; st > 0; st >>= 1) {
        if (c < st) red[c] += red[c + st];
        __syncthreads();
    }
    if (c == 0) out[g] = red[0] + bl[0];
}

// ---------------- launch ----------------

extern "C" void kernel_launch(void* const* d_in, const int* in_sizes, int n_in,
                              void* d_out, int out_size, void* d_ws, size_t ws_size,
                              hipStream_t stream) {
    const float* x  = (const float*)d_in[0];
    const int* ei   = (const int*)d_in[1];
    const int* batch = (const int*)d_in[2];
    const float* W1 = (const float*)d_in[3];
    const float* b1 = (const float*)d_in[4];
    const float* g1 = (const float*)d_in[5];
    const float* be1 = (const float*)d_in[6];
    const float* W2 = (const float*)d_in[7];
    const float* b2 = (const float*)d_in[8];
    const float* g2 = (const float*)d_in[9];
    const float* be2 = (const float*)d_in[10];
    const float* W3 = (const float*)d_in[11];
    const float* b3 = (const float*)d_in[12];
    const float* g3 = (const float*)d_in[13];
    const float* be3 = (const float*)d_in[14];
    const float* Wl = (const float*)d_in[15];
    const float* bl = (const float*)d_in[16];
    float* out = (float*)d_out;

    char* ws = (char*)d_ws;
    size_t off = 0;
    auto alloc = [&](size_t bytes) -> char* {
        char* p = ws + off;
        off = (off + bytes + 255) & ~(size_t)255;
        return p;
    };
    float* dinv    = (float*)alloc(N_NODES * 4);
    int* offs      = (int*)alloc(N_NODES * 4);
    int* inCnt     = (int*)alloc(N_NODES * 4);
    int* cursor    = (int*)alloc(NBUCKET * 4);
    int* bcsr      = (int*)alloc((size_t)NBUCKET * SLAB * 4);
    unsigned* csrp = (unsigned*)alloc((size_t)NBUCKET * SLAB * 4);
    float* statsP  = (float*)alloc(3 * SREP * 256 * 4);
    float* sums    = (float*)alloc(NGRAPH * FDIM * 4);
    unsigned short* Wt = (unsigned short*)alloc(3 * 16384 * 2);
    unsigned short* T16 = (unsigned short*)alloc((size_t)N_NODES * FDIM * 2);
    unsigned* H    = (unsigned*)alloc((size_t)N_NODES * 64 * 4);

    const int nb_nodes = (N_NODES + 255) / 256;   // 391
    const int nb_gemm = (N_NODES + 63) / 64;      // 1563
    const int nb_agg = (N_NODES / 32) * NSHARD;   // 25000
    const int nb_pool = (N_NODES + 63) / 64;      // 1563

    // preprocessing: bin -> per-bucket counting sort -> packed coef expansion
    initk<<<nb_nodes, 256, 0, stream>>>(statsP, sums, cursor);
    bink<<<NBINBLK, 256, 0, stream>>>(ei, cursor, bcsr);
    sortk<<<NBUCKET, 256, 0, stream>>>(cursor, bcsr, offs, inCnt, dinv);
    coefk<<<NBUCKET, 256, 0, stream>>>(cursor, bcsr, dinv, csrp);
    transposeW<<<24, 256, 0, stream>>>(W1, W2, W3, Wt);

    // layer 1
    gemmMF<0><<<nb_gemm, 256, 0, stream>>>(x, Wt, nullptr, nullptr, nullptr, T16);
    agg<<<nb_agg, 256, 0, stream>>>((const unsigned*)T16, csrp, offs, inCnt, dinv, b1, H, statsP);

    // layer 2 (BN1+ReLU fused into GEMM A-stage)
    gemmMF<1><<<nb_gemm, 256, 0, stream>>>(H, Wt + 16384, statsP, g1, be1, T16);
    agg<<<nb_agg, 256, 0, stream>>>((const unsigned*)T16, csrp, offs, inCnt, dinv, b2, H, statsP + SREP * 256);

    // layer 3
    gemmMF<1><<<nb_gemm, 256, 0, stream>>>(H, Wt + 32768, statsP + SREP * 256, g2, be2, T16);
    agg<<<nb_agg, 256, 0, stream>>>((const unsigned*)T16, csrp, offs, inCnt, dinv, b3, H, statsP + 2 * SREP * 256);

    // pool (BN3+ReLU fused) + linear
    poolsum<<<nb_pool, 128, 0, stream>>>(H, batch, statsP + 2 * SREP * 256, g3, be3, sums);
    finalk<<<NGRAPH, 128, 0, stream>>>(sums, batch, Wl, bl, out);
}

// Round 11
// 850.848 us; speedup vs baseline: 1.1285x; 1.1285x over previous
//
#include <hip/hip_runtime.h>
#include <hip/hip_bf16.h>
#include <hip/hip_fp16.h>

#define N_NODES 100000
#define E_EDGES 1600000
#define FDIM 128
#define NGRAPH 256
#define NPB 256            // nodes per bucket (dst >> 8)
#define NBUCKET 391        // ceil(N / 256)
#define SLAB 4800          // slab capacity (mean 4092, sigma ~64, +11 sigma)
#define BCHUNK 2048        // edges per bin block (small => parallelism)
#define NBINBLK ((E_EDGES + BCHUNK - 1) / BCHUNK)   // 782
#define LDSW 136           // padded bf16 row stride (128 + 8)
#define SREP 16            // stats replication
#define NSHARD 8           // channel shards (== XCD count)

typedef __attribute__((ext_vector_type(8))) short bf16x8;
typedef __attribute__((ext_vector_type(4))) float f32x4;

__device__ __forceinline__ unsigned pack_bf16(float a, float b) {
    unsigned ua = __float_as_uint(a);
    unsigned ub = __float_as_uint(b);
    ua = ua + 0x7fffu + ((ua >> 16) & 1u);
    ub = ub + 0x7fffu + ((ub >> 16) & 1u);
    return (ua >> 16) | (ub & 0xffff0000u);
}
__device__ __forceinline__ unsigned short bf16_1(float a) {
    unsigned ua = __float_as_uint(a);
    ua = ua + 0x7fffu + ((ua >> 16) & 1u);
    return (unsigned short)(ua >> 16);
}
__device__ __forceinline__ float bf_lo(unsigned u) { return __uint_as_float(u << 16); }
__device__ __forceinline__ float bf_hi(unsigned u) { return __uint_as_float(u & 0xffff0000u); }

// ---------------- preprocessing ----------------

__global__ void initk(float* __restrict__ statsP, float* __restrict__ sums,
                      int* __restrict__ cursor) {
    int i = blockIdx.x * blockDim.x + threadIdx.x;
    if (i < 3 * SREP * 256) statsP[i] = 0.0f;       // replicated stats slabs
    if (i < NGRAPH * FDIM) sums[i] = 0.0f;          // pooled sums
    if (i < NBUCKET) cursor[i] = i * SLAB;          // bucket slab cursors
}

// Phase 1: bin edges by dst bucket; clustered slab writes.
__global__ __launch_bounds__(256) void bink(const int* __restrict__ ei,
                                            int* __restrict__ cursor,
                                            int* __restrict__ bcsr) {
    __shared__ int hist[NBUCKET];
    __shared__ int base[NBUCKET];
    int t = threadIdx.x;
    for (int b = t; b < NBUCKET; b += 256) hist[b] = 0;
    __syncthreads();
    int e0 = blockIdx.x * BCHUNK;
    int e1 = e0 + BCHUNK; if (e1 > E_EDGES) e1 = E_EDGES;
    for (int e = e0 + t; e < e1; e += 256) {
        atomicAdd(&hist[ei[E_EDGES + e] >> 8], 1);
    }
    __syncthreads();
    for (int b = t; b < NBUCKET; b += 256) {
        int h = hist[b];
        base[b] = h ? atomicAdd(&cursor[b], h) : 0;
        hist[b] = 0;
    }
    __syncthreads();
    for (int e = e0 + t; e < e1; e += 256) {
        int s = ei[e];
        int d = ei[E_EDGES + e];
        int bk = d >> 8;
        int lp = atomicAdd(&hist[bk], 1);
        int pos = base[bk] + lp;
        if (pos < (bk + 1) * SLAB)                    // overflow guard
            bcsr[pos] = s | ((d & 255) << 17);
    }
}

// Phase 2: per-bucket LDS counting sort -> per-node grouping (in place, keeps
// dst-local bits), per-node offsets, in-counts, and dinv.
__global__ __launch_bounds__(256) void sortk(const int* __restrict__ cursor,
                                             int* __restrict__ bcsr,
                                             int* __restrict__ offs,
                                             int* __restrict__ inCnt,
                                             float* __restrict__ dinv) {
    __shared__ int ent[SLAB];      // 19.2 KB
    __shared__ int hist[NPB];
    __shared__ int hcur[NPB];
    __shared__ int htmp[NPB];
    int t = threadIdx.x;
    int bk = blockIdx.x;
    int slab = bk * SLAB;
    int cnt = cursor[bk] - slab;
    if (cnt > SLAB) cnt = SLAB;
    hist[t] = 0;
    __syncthreads();
    for (int i = t; i < cnt; i += 256) {
        int v = bcsr[slab + i];
        ent[i] = v;
        atomicAdd(&hist[v >> 17], 1);
    }
    __syncthreads();
    int myc = hist[t];
    htmp[t] = myc;
    __syncthreads();
    for (int st = 1; st < 256; st <<= 1) {
        int x = htmp[t];
        int y = (t >= st) ? htmp[t - st] : 0;
        __syncthreads();
        htmp[t] = x + y;
        __syncthreads();
    }
    int excl = htmp[t] - myc;
    hist[t] = excl;                 // reuse as scatter base
    hcur[t] = 0;
    int gn = bk * NPB + t;
    if (gn < N_NODES) {
        inCnt[gn] = myc;
        offs[gn] = slab + excl;
        dinv[gn] = rsqrtf((float)(1 + myc));   // +1 self-loop
    }
    __syncthreads();
    for (int i = t; i < cnt; i += 256) {
        int v = ent[i];
        int dl = v >> 17;
        int lp = atomicAdd(&hcur[dl], 1);
        bcsr[slab + hist[dl] + lp] = v;        // keep dl bits for coefk
    }
}

// Phase 3: pack to 4B entries: src(17) | fp16(coef)(15, sign always 0).
__global__ __launch_bounds__(256) void coefk(const int* __restrict__ cursor,
                                             const int* __restrict__ bcsr,
                                             const float* __restrict__ dinv,
                                             unsigned* __restrict__ csrp) {
    int bk = blockIdx.x;
    int slab = bk * SLAB;
    int cnt = cursor[bk] - slab;
    if (cnt > SLAB) cnt = SLAB;
    for (int i = threadIdx.x; i < cnt; i += 256) {
        int v = bcsr[slab + i];
        int s = v & 0x1FFFF;
        int d = bk * NPB + (v >> 17);
        float coef = dinv[s] * dinv[d];
        unsigned hb = (unsigned)__half_as_ushort(__float2half(coef));  // sign=0
        csrp[slab + i] = (unsigned)s | (hb << 17);
    }
}

// W^T (bf16) precompute: Wt[widx][n][k] = bf16(W[k][n])
__global__ __launch_bounds__(256) void transposeW(const float* __restrict__ W1,
                                                  const float* __restrict__ W2,
                                                  const float* __restrict__ W3,
                                                  unsigned short* __restrict__ Wt) {
    int b = blockIdx.x;
    int widx = b >> 3;
    int n0 = (b & 7) * 16;
    const float* W = (widx == 0) ? W1 : (widx == 1) ? W2 : W3;
    unsigned short* dst = Wt + widx * 16384;
    int t = threadIdx.x;
    int n = n0 + (t & 15);
#pragma unroll
    for (int i = 0; i < 8; i++) {
        int k = (t >> 4) + i * 16;
        dst[n * 128 + k] = bf16_1(W[k * 128 + n]);
    }
}

// ---------------- MFMA GEMM: T_bf16 = act(A[N,128]) @ W, SHARD-MAJOR output ----
// MODE 0: A fp32, no BN (layer 1). MODE 1: A bf16 (uint-packed), BN+ReLU fused.
// Output layout: T[shard][node][16ch] (shard = col>>4) so each shard slice is a
// contiguous 3.2 MB region (fits one XCD's 4 MiB L2).

template <int MODE>
__global__ __launch_bounds__(256, 2) void gemmMF(const void* __restrict__ Ain,
                                                 const unsigned short* __restrict__ Wt,
                                                 const float* __restrict__ statsP,
                                                 const float* __restrict__ g,
                                                 const float* __restrict__ be,
                                                 unsigned short* __restrict__ outT) {
    __shared__ unsigned short sA[64 * LDSW];
    __shared__ unsigned short sW[128 * LDSW];
    __shared__ float sScale[FDIM], sBias[FDIM];
    int tid = threadIdx.x;
    if (MODE == 1) {
        if (tid < FDIM) {
            float s = 0.f, q = 0.f;
#pragma unroll
            for (int r = 0; r < SREP; r++) {
                s += statsP[r * 256 + tid];
                q += statsP[r * 256 + 128 + tid];
            }
            float mean = s * (1.0f / N_NODES);
            float var = q * (1.0f / N_NODES) - mean * mean;
            float sc = g[tid] * rsqrtf(var + 1e-5f);
            sScale[tid] = sc;
            sBias[tid] = be[tid] - mean * sc;
        }
        __syncthreads();
    }
    int row0 = blockIdx.x * 64;
    {
        const uint4* Wt4 = (const uint4*)Wt;
#pragma unroll
        for (int i = 0; i < 8; i++) {
            int flat = tid + 256 * i;        // 0..2047
            int r = flat >> 4, c8 = flat & 15;
            uint4 v = Wt4[flat];
            *(uint4*)&sW[r * LDSW + c8 * 8] = v;
        }
    }
    if (MODE == 0) {
        const float4* A4 = (const float4*)Ain;
#pragma unroll
        for (int i = 0; i < 8; i++) {
            int flat = tid + 256 * i;        // 0..2047
            int r = flat >> 5, c4 = flat & 31;
            int grow = row0 + r;
            float4 v = make_float4(0.f, 0.f, 0.f, 0.f);
            if (grow < N_NODES) v = A4[grow * 32 + c4];
            uint2 p;
            p.x = pack_bf16(v.x, v.y);
            p.y = pack_bf16(v.z, v.w);
            *(uint2*)&sA[r * LDSW + c4 * 4] = p;
        }
    } else {
        const uint2* A2 = (const uint2*)Ain;
#pragma unroll
        for (int i = 0; i < 8; i++) {
            int flat = tid + 256 * i;        // 0..2047
            int r = flat >> 5, c4 = flat & 31;
            int grow = row0 + r;
            uint2 u = make_uint2(0u, 0u);
            if (grow < N_NODES) u = A2[grow * 32 + c4];
            int ch = c4 * 4;
            float vx = fmaxf(bf_lo(u.x) * sScale[ch + 0] + sBias[ch + 0], 0.f);
            float vy = fmaxf(bf_hi(u.x) * sScale[ch + 1] + sBias[ch + 1], 0.f);
            float vz = fmaxf(bf_lo(u.y) * sScale[ch + 2] + sBias[ch + 2], 0.f);
            float vw = fmaxf(bf_hi(u.y) * sScale[ch + 3] + sBias[ch + 3], 0.f);
            uint2 p;
            p.x = pack_bf16(vx, vy);
            p.y = pack_bf16(vz, vw);
            *(uint2*)&sA[r * LDSW + c4 * 4] = p;
        }
    }
    __syncthreads();

    int lane = tid & 63;
    int w = tid >> 6;         // wave id: cols w*32..w*32+31
    int rbase = lane & 15;
    int kgrp = lane >> 4;     // 0..3
    f32x4 acc[4][2];
#pragma unroll
    for (int mf = 0; mf < 4; mf++)
#pragma unroll
        for (int nf = 0; nf < 2; nf++) acc[mf][nf] = (f32x4){0.f, 0.f, 0.f, 0.f};

#pragma unroll
    for (int kk = 0; kk < 4; kk++) {
        int kb = kk * 32 + kgrp * 8;
        bf16x8 af[4], bfr[2];
#pragma unroll
        for (int mf = 0; mf < 4; mf++)
            af[mf] = *(const bf16x8*)&sA[(mf * 16 + rbase) * LDSW + kb];
#pragma unroll
        for (int nf = 0; nf < 2; nf++)
            bfr[nf] = *(const bf16x8*)&sW[(w * 32 + nf * 16 + rbase) * LDSW + kb];
#pragma unroll
        for (int mf = 0; mf < 4; mf++)
#pragma unroll
            for (int nf = 0; nf < 2; nf++)
                acc[mf][nf] = __builtin_amdgcn_mfma_f32_16x16x32_bf16(
                    af[mf], bfr[nf], acc[mf][nf], 0, 0, 0);
    }
    // epilogue: shard-major store. col block of 16 lies in exactly one shard.
#pragma unroll
    for (int mf = 0; mf < 4; mf++) {
#pragma unroll
        for (int nf = 0; nf < 2; nf++) {
            int col = w * 32 + nf * 16 + rbase;
            int shard = col >> 4;
            int cch = col & 15;
#pragma unroll
            for (int j = 0; j < 4; j++) {
                int grow = row0 + mf * 16 + kgrp * 4 + j;
                if (grow < N_NODES) {
                    outT[((size_t)shard * N_NODES + grow) * 16 + cch] = bf16_1(acc[mf][nf][j]);
                }
            }
        }
    }
}

// ---------------- edge aggregation: XCD-pinned channel shards (shard-major T) --
// grid = 3125*8; shard = blockIdx & 7 (round-robin -> one shard per XCD; slice
// is CONTIGUOUS 3.2 MB -> L2-resident). 4 waves x 8 nodes per block.
// lane: esub = lane>>3 (edge slot), ch = lane&7 (uint within slice row).

__global__ __launch_bounds__(256) void agg(const unsigned* __restrict__ t,
                                           const unsigned* __restrict__ csrp,
                                           const int* __restrict__ offs,
                                           const int* __restrict__ inCnt,
                                           const float* __restrict__ dinv,
                                           const float* __restrict__ bias,
                                           unsigned* __restrict__ outH,
                                           float* __restrict__ statsP) {
    int tid = threadIdx.x;
    int lane = tid & 63;
    int wid = tid >> 6;
    int shard = blockIdx.x & (NSHARD - 1);
    int nbase = (blockIdx.x >> 3) * 32;
    int esub = lane >> 3;
    int ch = lane & 7;
    const unsigned* tsl = t + (size_t)shard * N_NODES * 8;   // this XCD's slice
    const float2* bias2 = (const float2*)bias;
    float2 b = bias2[shard * 8 + ch];
    float s0 = 0.f, s1 = 0.f, q0 = 0.f, q1 = 0.f;
    for (int it = 0; it < 8; it++) {
        int node = __builtin_amdgcn_readfirstlane(nbase + wid * 8 + it);
        float di = dinv[node];
        int start = offs[node];
        int cnt = inCnt[node];
        float a0 = 0.f, a1 = 0.f;
        for (int e = 0; e < cnt; e += 16) {
            int i0 = e + esub;
            int i1 = e + 8 + esub;
            unsigned v0 = (i0 < cnt) ? __builtin_nontemporal_load(&csrp[start + i0]) : 0u;
            unsigned v1 = (i1 < cnt) ? __builtin_nontemporal_load(&csrp[start + i1]) : 0u;
            unsigned u0 = tsl[(v0 & 0x1FFFF) * 8 + ch];
            unsigned u1 = tsl[(v1 & 0x1FFFF) * 8 + ch];
            float f0 = __half2float(__ushort_as_half((unsigned short)(v0 >> 17)));
            float f1 = __half2float(__ushort_as_half((unsigned short)(v1 >> 17)));
            a0 += f0 * bf_lo(u0); a1 += f0 * bf_hi(u0);
            a0 += f1 * bf_lo(u1); a1 += f1 * bf_hi(u1);
        }
        // fold the 8 edge-slot groups (preserve ch bits 0..2)
        a0 += __shfl_xor(a0, 8, 64);  a1 += __shfl_xor(a1, 8, 64);
        a0 += __shfl_xor(a0, 16, 64); a1 += __shfl_xor(a1, 16, 64);
        a0 += __shfl_xor(a0, 32, 64); a1 += __shfl_xor(a1, 32, 64);
        // self-loop + bias
        unsigned su = tsl[node * 8 + ch];
        float cs = di * di;
        a0 += cs * bf_lo(su) + b.x;
        a1 += cs * bf_hi(su) + b.y;
        if (esub == 0) {
            outH[node * 64 + shard * 8 + ch] = pack_bf16(a0, a1);
            s0 += a0; q0 += a0 * a0;
            s1 += a1; q1 += a1 * a1;
        }
    }
    // stats: 16 channels per block
    __shared__ float sS[64], sQ[64];
    if (esub == 0) {
        sS[wid * 16 + 2 * ch + 0] = s0; sQ[wid * 16 + 2 * ch + 0] = q0;
        sS[wid * 16 + 2 * ch + 1] = s1; sQ[wid * 16 + 2 * ch + 1] = q1;
    }
    __syncthreads();
    if (tid < 16) {
        float S = sS[tid] + sS[16 + tid] + sS[32 + tid] + sS[48 + tid];
        float Q = sQ[tid] + sQ[16 + tid] + sQ[32 + tid] + sQ[48 + tid];
        int gch = shard * 16 + tid;
        float* p = statsP + ((blockIdx.x >> 3) & (SREP - 1)) * 256;
        atomicAdd(&p[gch], S);
        atomicAdd(&p[128 + gch], Q);
    }
}

// ---------------- pool phase 1: BN3+ReLU + segment-sum (bf16 H) ----------------

__global__ __launch_bounds__(128) void poolsum(const unsigned* __restrict__ h,
                                               const int* __restrict__ batch,
                                               const float* __restrict__ statsP,
                                               const float* __restrict__ g3,
                                               const float* __restrict__ be3,
                                               float* __restrict__ sums) {
    int c = threadIdx.x;
    int base = blockIdx.x * 64;
    float s = 0.f, q = 0.f;
#pragma unroll
    for (int r = 0; r < SREP; r++) {
        s += statsP[r * 256 + c];
        q += statsP[r * 256 + 128 + c];
    }
    float mean = s * (1.0f / N_NODES);
    float var = q * (1.0f / N_NODES) - mean * mean;
    float sc = g3[c] * rsqrtf(var + 1e-5f);
    float bi = be3[c] - mean * sc;
    __shared__ int sb[64];
    if (c < 64) {
        int idx = base + c;
        sb[c] = (idx < N_NODES) ? batch[idx] : -1;
    }
    __syncthreads();
    float acc = 0.f;
    int gcur = sb[0];
    int half = c & 1;
    int cu = c >> 1;
    for (int r = 0; r < 64; r++) {
        int idx = base + r;
        if (idx >= N_NODES) break;
        int gr = sb[r];
        if (gr != gcur) {
            atomicAdd(&sums[gcur * FDIM + c], acc);
            acc = 0.f;
            gcur = gr;
        }
        unsigned u = h[(size_t)idx * 64 + cu];
        float v = half ? bf_hi(u) : bf_lo(u);
        acc += fmaxf(v * sc + bi, 0.f);
    }
    atomicAdd(&sums[gcur * FDIM + c], acc);
}

// ---------------- pool phase 2: divide + final linear ----------------

__global__ __launch_bounds__(128) void finalk(const float* __restrict__ sums,
                                              const int* __restrict__ batch,
                                              const float* __restrict__ Wl,
                                              const float* __restrict__ bl,
                                              float* __restrict__ out) {
    int g = blockIdx.x;
    int c = threadIdx.x;
    int lo = 0, hi = N_NODES;
    while (lo < hi) { int m = (lo + hi) >> 1; if (batch[m] < g) lo = m + 1; else hi = m; }
    int start = lo;
    lo = start; hi = N_NODES;
    while (lo < hi) { int m = (lo + hi) >> 1; if (batch[m] < g + 1) lo = m + 1; else hi = m; }
    int cnt = lo - start;
    float v = sums[g * FDIM + c] / fmaxf((float)cnt, 1.0f) * Wl[c];
    __shared__ float red[FDIM];
    red[c] = v;
    __syncthreads();
    for (int st = 64; st > 0; st >>= 1) {
        if (c < st) red[c] += red[c + st];
        __syncthreads();
    }
    if (c == 0) out[g] = red[0] + bl[0];
}

// ---------------- launch ----------------

extern "C" void kernel_launch(void* const* d_in, const int* in_sizes, int n_in,
                              void* d_out, int out_size, void* d_ws, size_t ws_size,
                              hipStream_t stream) {
    const float* x  = (const float*)d_in[0];
    const int* ei   = (const int*)d_in[1];
    const int* batch = (const int*)d_in[2];
    const float* W1 = (const float*)d_in[3];
    const float* b1 = (const float*)d_in[4];
    const float* g1 = (const float*)d_in[5];
    const float* be1 = (const float*)d_in[6];
    const float* W2 = (const float*)d_in[7];
    const float* b2 = (const float*)d_in[8];
    const float* g2 = (const float*)d_in[9];
    const float* be2 = (const float*)d_in[10];
    const float* W3 = (const float*)d_in[11];
    const float* b3 = (const float*)d_in[12];
    const float* g3 = (const float*)d_in[13];
    const float* be3 = (const float*)d_in[14];
    const float* Wl = (const float*)d_in[15];
    const float* bl = (const float*)d_in[16];
    float* out = (float*)d_out;

    char* ws = (char*)d_ws;
    size_t off = 0;
    auto alloc = [&](size_t bytes) -> char* {
        char* p = ws + off;
        off = (off + bytes + 255) & ~(size_t)255;
        return p;
    };
    float* dinv    = (float*)alloc(N_NODES * 4);
    int* offs      = (int*)alloc(N_NODES * 4);
    int* inCnt     = (int*)alloc(N_NODES * 4);
    int* cursor    = (int*)alloc(NBUCKET * 4);
    int* bcsr      = (int*)alloc((size_t)NBUCKET * SLAB * 4);
    unsigned* csrp = (unsigned*)alloc((size_t)NBUCKET * SLAB * 4);
    float* statsP  = (float*)alloc(3 * SREP * 256 * 4);
    float* sums    = (float*)alloc(NGRAPH * FDIM * 4);
    unsigned short* Wt = (unsigned short*)alloc(3 * 16384 * 2);
    unsigned short* T16 = (unsigned short*)alloc((size_t)N_NODES * FDIM * 2);  // shard-major
    unsigned* H    = (unsigned*)alloc((size_t)N_NODES * 64 * 4);

    const int nb_nodes = (N_NODES + 255) / 256;   // 391
    const int nb_gemm = (N_NODES + 63) / 64;      // 1563
    const int nb_agg = (N_NODES / 32) * NSHARD;   // 25000 (multiple of 8)
    const int nb_pool = (N_NODES + 63) / 64;      // 1563

    // preprocessing: bin -> per-bucket counting sort -> packed coef expansion
    initk<<<nb_nodes, 256, 0, stream>>>(statsP, sums, cursor);
    bink<<<NBINBLK, 256, 0, stream>>>(ei, cursor, bcsr);
    sortk<<<NBUCKET, 256, 0, stream>>>(cursor, bcsr, offs, inCnt, dinv);
    coefk<<<NBUCKET, 256, 0, stream>>>(cursor, bcsr, dinv, csrp);
    transposeW<<<24, 256, 0, stream>>>(W1, W2, W3, Wt);

    // layer 1
    gemmMF<0><<<nb_gemm, 256, 0, stream>>>(x, Wt, nullptr, nullptr, nullptr, T16);
    agg<<<nb_agg, 256, 0, stream>>>((const unsigned*)T16, csrp, offs, inCnt, dinv, b1, H, statsP);

    // layer 2 (BN1+ReLU fused into GEMM A-stage)
    gemmMF<1><<<nb_gemm, 256, 0, stream>>>(H, Wt + 16384, statsP, g1, be1, T16);
    agg<<<nb_agg, 256, 0, stream>>>((const unsigned*)T16, csrp, offs, inCnt, dinv, b2, H, statsP + SREP * 256);

    // layer 3
    gemmMF<1><<<nb_gemm, 256, 0, stream>>>(H, Wt + 32768, statsP + SREP * 256, g2, be2, T16);
    agg<<<nb_agg, 256, 0, stream>>>((const unsigned*)T16, csrp, offs, inCnt, dinv, b3, H, statsP + 2 * SREP * 256);

    // pool (BN3+ReLU fused) + linear
    poolsum<<<nb_pool, 128, 0, stream>>>(H, batch, statsP + 2 * SREP * 256, g3, be3, sums);
    finalk<<<NGRAPH, 128, 0, stream>>>(sums, batch, Wl, bl, out);
}

// Round 12
// 736.647 us; speedup vs baseline: 1.3034x; 1.1550x over previous
//
#include <hip/hip_runtime.h>
#include <hip/hip_bf16.h>
#include <hip/hip_fp16.h>

#define N_NODES 100000
#define E_EDGES 1600000
#define FDIM 128
#define NGRAPH 256
#define NPB 256            // nodes per bucket (dst >> 8)
#define NBUCKET 391        // ceil(N / 256)
#define SLAB 4800          // slab capacity (mean 4092, sigma ~64, +11 sigma)
#define BCHUNK 2048        // edges per bin block (small => parallelism)
#define NBINBLK ((E_EDGES + BCHUNK - 1) / BCHUNK)   // 782
#define LDSW 136           // padded bf16 row stride (128 + 8)
#define SREP 16            // stats replication
#define NSHARD 8           // channel shards (== XCD count)
#define ECAP 1024          // LDS CSR stage capacity per 32-node chunk (+22 sigma)

typedef __attribute__((ext_vector_type(8))) short bf16x8;
typedef __attribute__((ext_vector_type(4))) float f32x4;

__device__ __forceinline__ unsigned pack_bf16(float a, float b) {
    unsigned ua = __float_as_uint(a);
    unsigned ub = __float_as_uint(b);
    ua = ua + 0x7fffu + ((ua >> 16) & 1u);
    ub = ub + 0x7fffu + ((ub >> 16) & 1u);
    return (ua >> 16) | (ub & 0xffff0000u);
}
__device__ __forceinline__ unsigned short bf16_1(float a) {
    unsigned ua = __float_as_uint(a);
    ua = ua + 0x7fffu + ((ua >> 16) & 1u);
    return (unsigned short)(ua >> 16);
}
__device__ __forceinline__ float bf_lo(unsigned u) { return __uint_as_float(u << 16); }
__device__ __forceinline__ float bf_hi(unsigned u) { return __uint_as_float(u & 0xffff0000u); }

// ---------------- preprocessing ----------------

__global__ void initk(float* __restrict__ statsP, float* __restrict__ sums,
                      int* __restrict__ cursor) {
    int i = blockIdx.x * blockDim.x + threadIdx.x;
    if (i < 3 * SREP * 256) statsP[i] = 0.0f;       // replicated stats slabs
    if (i < NGRAPH * FDIM) sums[i] = 0.0f;          // pooled sums
    if (i < NBUCKET) cursor[i] = i * SLAB;          // bucket slab cursors
}

// Phase 1: bin edges by dst bucket; clustered slab writes.
__global__ __launch_bounds__(256) void bink(const int* __restrict__ ei,
                                            int* __restrict__ cursor,
                                            int* __restrict__ bcsr) {
    __shared__ int hist[NBUCKET];
    __shared__ int base[NBUCKET];
    int t = threadIdx.x;
    for (int b = t; b < NBUCKET; b += 256) hist[b] = 0;
    __syncthreads();
    int e0 = blockIdx.x * BCHUNK;
    int e1 = e0 + BCHUNK; if (e1 > E_EDGES) e1 = E_EDGES;
    for (int e = e0 + t; e < e1; e += 256) {
        atomicAdd(&hist[ei[E_EDGES + e] >> 8], 1);
    }
    __syncthreads();
    for (int b = t; b < NBUCKET; b += 256) {
        int h = hist[b];
        base[b] = h ? atomicAdd(&cursor[b], h) : 0;
        hist[b] = 0;
    }
    __syncthreads();
    for (int e = e0 + t; e < e1; e += 256) {
        int s = ei[e];
        int d = ei[E_EDGES + e];
        int bk = d >> 8;
        int lp = atomicAdd(&hist[bk], 1);
        int pos = base[bk] + lp;
        if (pos < (bk + 1) * SLAB)                    // overflow guard
            bcsr[pos] = s | ((d & 255) << 17);
    }
}

// Phase 2: per-bucket LDS counting sort -> per-node grouping (in place, keeps
// dst-local bits), per-node offsets, in-counts, and dinv.
__global__ __launch_bounds__(256) void sortk(const int* __restrict__ cursor,
                                             int* __restrict__ bcsr,
                                             int* __restrict__ offs,
                                             int* __restrict__ inCnt,
                                             float* __restrict__ dinv) {
    __shared__ int ent[SLAB];      // 19.2 KB
    __shared__ int hist[NPB];
    __shared__ int hcur[NPB];
    __shared__ int htmp[NPB];
    int t = threadIdx.x;
    int bk = blockIdx.x;
    int slab = bk * SLAB;
    int cnt = cursor[bk] - slab;
    if (cnt > SLAB) cnt = SLAB;
    hist[t] = 0;
    __syncthreads();
    for (int i = t; i < cnt; i += 256) {
        int v = bcsr[slab + i];
        ent[i] = v;
        atomicAdd(&hist[v >> 17], 1);
    }
    __syncthreads();
    int myc = hist[t];
    htmp[t] = myc;
    __syncthreads();
    for (int st = 1; st < 256; st <<= 1) {
        int x = htmp[t];
        int y = (t >= st) ? htmp[t - st] : 0;
        __syncthreads();
        htmp[t] = x + y;
        __syncthreads();
    }
    int excl = htmp[t] - myc;
    hist[t] = excl;                 // reuse as scatter base
    hcur[t] = 0;
    int gn = bk * NPB + t;
    if (gn < N_NODES) {
        inCnt[gn] = myc;
        offs[gn] = slab + excl;
        dinv[gn] = rsqrtf((float)(1 + myc));   // +1 self-loop
    }
    __syncthreads();
    for (int i = t; i < cnt; i += 256) {
        int v = ent[i];
        int dl = v >> 17;
        int lp = atomicAdd(&hcur[dl], 1);
        bcsr[slab + hist[dl] + lp] = v;        // keep dl bits for coefk
    }
}

// Phase 3: pack to 4B entries: src(17) | fp16(coef)(15, sign always 0).
__global__ __launch_bounds__(256) void coefk(const int* __restrict__ cursor,
                                             const int* __restrict__ bcsr,
                                             const float* __restrict__ dinv,
                                             unsigned* __restrict__ csrp) {
    int bk = blockIdx.x;
    int slab = bk * SLAB;
    int cnt = cursor[bk] - slab;
    if (cnt > SLAB) cnt = SLAB;
    for (int i = threadIdx.x; i < cnt; i += 256) {
        int v = bcsr[slab + i];
        int s = v & 0x1FFFF;
        int d = bk * NPB + (v >> 17);
        float coef = dinv[s] * dinv[d];
        unsigned hb = (unsigned)__half_as_ushort(__float2half(coef));  // sign=0
        csrp[slab + i] = (unsigned)s | (hb << 17);
    }
}

// W^T (bf16) precompute: Wt[widx][n][k] = bf16(W[k][n])
__global__ __launch_bounds__(256) void transposeW(const float* __restrict__ W1,
                                                  const float* __restrict__ W2,
                                                  const float* __restrict__ W3,
                                                  unsigned short* __restrict__ Wt) {
    int b = blockIdx.x;
    int widx = b >> 3;
    int n0 = (b & 7) * 16;
    const float* W = (widx == 0) ? W1 : (widx == 1) ? W2 : W3;
    unsigned short* dst = Wt + widx * 16384;
    int t = threadIdx.x;
    int n = n0 + (t & 15);
#pragma unroll
    for (int i = 0; i < 8; i++) {
        int k = (t >> 4) + i * 16;
        dst[n * 128 + k] = bf16_1(W[k * 128 + n]);
    }
}

// ---------------- MFMA GEMM: T_bf16 = act(A[N,128]) @ W, SHARD-MAJOR output ----
// MODE 0: A fp32, no BN (layer 1). MODE 1: A bf16 (uint-packed), BN+ReLU fused.
// Output layout: T[shard][node][16ch] (shard = col>>4) so each shard slice is a
// contiguous 3.2 MB region (fits one XCD's 4 MiB L2).

template <int MODE>
__global__ __launch_bounds__(256, 2) void gemmMF(const void* __restrict__ Ain,
                                                 const unsigned short* __restrict__ Wt,
                                                 const float* __restrict__ statsP,
                                                 const float* __restrict__ g,
                                                 const float* __restrict__ be,
                                                 unsigned short* __restrict__ outT) {
    __shared__ unsigned short sA[64 * LDSW];
    __shared__ unsigned short sW[128 * LDSW];
    __shared__ float sScale[FDIM], sBias[FDIM];
    int tid = threadIdx.x;
    if (MODE == 1) {
        if (tid < FDIM) {
            float s = 0.f, q = 0.f;
#pragma unroll
            for (int r = 0; r < SREP; r++) {
                s += statsP[r * 256 + tid];
                q += statsP[r * 256 + 128 + tid];
            }
            float mean = s * (1.0f / N_NODES);
            float var = q * (1.0f / N_NODES) - mean * mean;
            float sc = g[tid] * rsqrtf(var + 1e-5f);
            sScale[tid] = sc;
            sBias[tid] = be[tid] - mean * sc;
        }
        __syncthreads();
    }
    int row0 = blockIdx.x * 64;
    {
        const uint4* Wt4 = (const uint4*)Wt;
#pragma unroll
        for (int i = 0; i < 8; i++) {
            int flat = tid + 256 * i;        // 0..2047
            int r = flat >> 4, c8 = flat & 15;
            uint4 v = Wt4[flat];
            *(uint4*)&sW[r * LDSW + c8 * 8] = v;
        }
    }
    if (MODE == 0) {
        const float4* A4 = (const float4*)Ain;
#pragma unroll
        for (int i = 0; i < 8; i++) {
            int flat = tid + 256 * i;        // 0..2047
            int r = flat >> 5, c4 = flat & 31;
            int grow = row0 + r;
            float4 v = make_float4(0.f, 0.f, 0.f, 0.f);
            if (grow < N_NODES) v = A4[grow * 32 + c4];
            uint2 p;
            p.x = pack_bf16(v.x, v.y);
            p.y = pack_bf16(v.z, v.w);
            *(uint2*)&sA[r * LDSW + c4 * 4] = p;
        }
    } else {
        const uint2* A2 = (const uint2*)Ain;
#pragma unroll
        for (int i = 0; i < 8; i++) {
            int flat = tid + 256 * i;        // 0..2047
            int r = flat >> 5, c4 = flat & 31;
            int grow = row0 + r;
            uint2 u = make_uint2(0u, 0u);
            if (grow < N_NODES) u = A2[grow * 32 + c4];
            int ch = c4 * 4;
            float vx = fmaxf(bf_lo(u.x) * sScale[ch + 0] + sBias[ch + 0], 0.f);
            float vy = fmaxf(bf_hi(u.x) * sScale[ch + 1] + sBias[ch + 1], 0.f);
            float vz = fmaxf(bf_lo(u.y) * sScale[ch + 2] + sBias[ch + 2], 0.f);
            float vw = fmaxf(bf_hi(u.y) * sScale[ch + 3] + sBias[ch + 3], 0.f);
            uint2 p;
            p.x = pack_bf16(vx, vy);
            p.y = pack_bf16(vz, vw);
            *(uint2*)&sA[r * LDSW + c4 * 4] = p;
        }
    }
    __syncthreads();

    int lane = tid & 63;
    int w = tid >> 6;         // wave id: cols w*32..w*32+31
    int rbase = lane & 15;
    int kgrp = lane >> 4;     // 0..3
    f32x4 acc[4][2];
#pragma unroll
    for (int mf = 0; mf < 4; mf++)
#pragma unroll
        for (int nf = 0; nf < 2; nf++) acc[mf][nf] = (f32x4){0.f, 0.f, 0.f, 0.f};

#pragma unroll
    for (int kk = 0; kk < 4; kk++) {
        int kb = kk * 32 + kgrp * 8;
        bf16x8 af[4], bfr[2];
#pragma unroll
        for (int mf = 0; mf < 4; mf++)
            af[mf] = *(const bf16x8*)&sA[(mf * 16 + rbase) * LDSW + kb];
#pragma unroll
        for (int nf = 0; nf < 2; nf++)
            bfr[nf] = *(const bf16x8*)&sW[(w * 32 + nf * 16 + rbase) * LDSW + kb];
#pragma unroll
        for (int mf = 0; mf < 4; mf++)
#pragma unroll
            for (int nf = 0; nf < 2; nf++)
                acc[mf][nf] = __builtin_amdgcn_mfma_f32_16x16x32_bf16(
                    af[mf], bfr[nf], acc[mf][nf], 0, 0, 0);
    }
    // epilogue: shard-major store. col block of 16 lies in exactly one shard.
#pragma unroll
    for (int mf = 0; mf < 4; mf++) {
#pragma unroll
        for (int nf = 0; nf < 2; nf++) {
            int col = w * 32 + nf * 16 + rbase;
            int shard = col >> 4;
            int cch = col & 15;
#pragma unroll
            for (int j = 0; j < 4; j++) {
                int grow = row0 + mf * 16 + kgrp * 4 + j;
                if (grow < N_NODES) {
                    outT[((size_t)shard * N_NODES + grow) * 16 + cch] = bf16_1(acc[mf][nf][j]);
                }
            }
        }
    }
}

// ---------------- edge aggregation: XCD-pinned shards + LDS CSR staging -------
// grid = 3125*8; shard = blockIdx & 7 (round-robin -> one shard per XCD; slice
// contiguous 3.2 MB -> L2-resident). Block stages its 32 nodes' contiguous CSR
// range into LDS once, then runs 32-edge chunks with 4 independent L2 gathers.
// lane: esub = lane>>3 (edge slot), ch = lane&7 (uint within slice row).

__global__ __launch_bounds__(256) void agg(const unsigned* __restrict__ t,
                                           const unsigned* __restrict__ csrp,
                                           const int* __restrict__ offs,
                                           const int* __restrict__ inCnt,
                                           const float* __restrict__ dinv,
                                           const float* __restrict__ bias,
                                           unsigned* __restrict__ outH,
                                           float* __restrict__ statsP) {
    __shared__ unsigned eLds[ECAP];   // 4 KB
    __shared__ float sS[64], sQ[64];
    int tid = threadIdx.x;
    int lane = tid & 63;
    int wid = tid >> 6;
    int shard = blockIdx.x & (NSHARD - 1);
    int chunk = blockIdx.x >> 3;
    int node0 = chunk * 32;
    int esub = lane >> 3;
    int ch = lane & 7;
    const unsigned* tsl = t + (size_t)shard * N_NODES * 8;   // this XCD's slice

    // stage the chunk's contiguous CSR range (32 nodes, same bucket)
    int st0 = offs[node0];
    int totalE = offs[node0 + 31] + inCnt[node0 + 31] - st0;
    int nl = totalE < ECAP ? totalE : ECAP;
    for (int i = tid; i < nl; i += 256)
        eLds[i] = __builtin_nontemporal_load(&csrp[st0 + i]);
    __syncthreads();

    const float2* bias2 = (const float2*)bias;
    float2 b = bias2[shard * 8 + ch];
    float s0 = 0.f, s1 = 0.f, q0 = 0.f, q1 = 0.f;
    for (int it = 0; it < 8; it++) {
        int node = node0 + wid * 8 + it;          // wave-uniform
        float di = dinv[node];
        int ls = offs[node] - st0;
        int cnt = inCnt[node];
        float a0 = 0.f, a1 = 0.f;
        for (int e = 0; e < cnt; e += 32) {
            unsigned v0 = 0u, v1 = 0u, v2 = 0u, v3 = 0u;
            int i0 = e + 0 + esub, i1 = e + 8 + esub, i2 = e + 16 + esub, i3 = e + 24 + esub;
            if (i0 < cnt) { int li = ls + i0; v0 = (li < ECAP) ? eLds[li] : csrp[st0 + li]; }
            if (i1 < cnt) { int li = ls + i1; v1 = (li < ECAP) ? eLds[li] : csrp[st0 + li]; }
            if (i2 < cnt) { int li = ls + i2; v2 = (li < ECAP) ? eLds[li] : csrp[st0 + li]; }
            if (i3 < cnt) { int li = ls + i3; v3 = (li < ECAP) ? eLds[li] : csrp[st0 + li]; }
            // 4 independent gathers (v=0 sentinel -> row 0, coef 0, harmless)
            unsigned u0 = tsl[(v0 & 0x1FFFF) * 8 + ch];
            unsigned u1 = tsl[(v1 & 0x1FFFF) * 8 + ch];
            unsigned u2 = tsl[(v2 & 0x1FFFF) * 8 + ch];
            unsigned u3 = tsl[(v3 & 0x1FFFF) * 8 + ch];
            float f0 = __half2float(__ushort_as_half((unsigned short)(v0 >> 17)));
            float f1 = __half2float(__ushort_as_half((unsigned short)(v1 >> 17)));
            float f2 = __half2float(__ushort_as_half((unsigned short)(v2 >> 17)));
            float f3 = __half2float(__ushort_as_half((unsigned short)(v3 >> 17)));
            a0 += f0 * bf_lo(u0); a1 += f0 * bf_hi(u0);
            a0 += f1 * bf_lo(u1); a1 += f1 * bf_hi(u1);
            a0 += f2 * bf_lo(u2); a1 += f2 * bf_hi(u2);
            a0 += f3 * bf_lo(u3); a1 += f3 * bf_hi(u3);
        }
        // fold the 8 edge-slot groups (preserve ch bits 0..2)
        a0 += __shfl_xor(a0, 8, 64);  a1 += __shfl_xor(a1, 8, 64);
        a0 += __shfl_xor(a0, 16, 64); a1 += __shfl_xor(a1, 16, 64);
        a0 += __shfl_xor(a0, 32, 64); a1 += __shfl_xor(a1, 32, 64);
        // self-loop + bias
        unsigned su = tsl[node * 8 + ch];
        float cs = di * di;
        a0 += cs * bf_lo(su) + b.x;
        a1 += cs * bf_hi(su) + b.y;
        if (esub == 0) {
            outH[node * 64 + shard * 8 + ch] = pack_bf16(a0, a1);
            s0 += a0; q0 += a0 * a0;
            s1 += a1; q1 += a1 * a1;
        }
    }
    // stats: 16 channels per block
    if (esub == 0) {
        sS[wid * 16 + 2 * ch + 0] = s0; sQ[wid * 16 + 2 * ch + 0] = q0;
        sS[wid * 16 + 2 * ch + 1] = s1; sQ[wid * 16 + 2 * ch + 1] = q1;
    }
    __syncthreads();
    if (tid < 16) {
        float S = sS[tid] + sS[16 + tid] + sS[32 + tid] + sS[48 + tid];
        float Q = sQ[tid] + sQ[16 + tid] + sQ[32 + tid] + sQ[48 + tid];
        int gch = shard * 16 + tid;
        float* p = statsP + (chunk & (SREP - 1)) * 256;
        atomicAdd(&p[gch], S);
        atomicAdd(&p[128 + gch], Q);
    }
}

// ---------------- pool phase 1: BN3+ReLU + segment-sum (bf16 H) ----------------

__global__ __launch_bounds__(128) void poolsum(const unsigned* __restrict__ h,
                                               const int* __restrict__ batch,
                                               const float* __restrict__ statsP,
                                               const float* __restrict__ g3,
                                               const float* __restrict__ be3,
                                               float* __restrict__ sums) {
    int c = threadIdx.x;
    int base = blockIdx.x * 64;
    float s = 0.f, q = 0.f;
#pragma unroll
    for (int r = 0; r < SREP; r++) {
        s += statsP[r * 256 + c];
        q += statsP[r * 256 + 128 + c];
    }
    float mean = s * (1.0f / N_NODES);
    float var = q * (1.0f / N_NODES) - mean * mean;
    float sc = g3[c] * rsqrtf(var + 1e-5f);
    float bi = be3[c] - mean * sc;
    __shared__ int sb[64];
    if (c < 64) {
        int idx = base + c;
        sb[c] = (idx < N_NODES) ? batch[idx] : -1;
    }
    __syncthreads();
    float acc = 0.f;
    int gcur = sb[0];
    int half = c & 1;
    int cu = c >> 1;
    for (int r = 0; r < 64; r++) {
        int idx = base + r;
        if (idx >= N_NODES) break;
        int gr = sb[r];
        if (gr != gcur) {
            atomicAdd(&sums[gcur * FDIM + c], acc);
            acc = 0.f;
            gcur = gr;
        }
        unsigned u = h[(size_t)idx * 64 + cu];
        float v = half ? bf_hi(u) : bf_lo(u);
        acc += fmaxf(v * sc + bi, 0.f);
    }
    atomicAdd(&sums[gcur * FDIM + c], acc);
}

// ---------------- pool phase 2: divide + final linear ----------------

__global__ __launch_bounds__(128) void finalk(const float* __restrict__ sums,
                                              const int* __restrict__ batch,
                                              const float* __restrict__ Wl,
                                              const float* __restrict__ bl,
                                              float* __restrict__ out) {
    int g = blockIdx.x;
    int c = threadIdx.x;
    int lo = 0, hi = N_NODES;
    while (lo < hi) { int m = (lo + hi) >> 1; if (batch[m] < g) lo = m + 1; else hi = m; }
    int start = lo;
    lo = start; hi = N_NODES;
    while (lo < hi) { int m = (lo + hi) >> 1; if (batch[m] < g + 1) lo = m + 1; else hi = m; }
    int cnt = lo - start;
    float v = sums[g * FDIM + c] / fmaxf((float)cnt, 1.0f) * Wl[c];
    __shared__ float red[FDIM];
    red[c] = v;
    __syncthreads();
    for (int st = 64; st > 0; st >>= 1) {
        if (c < st) red[c] += red[c + st];
        __syncthreads();
    }
    if (c == 0) out[g] = red[0] + bl[0];
}

// ---------------- launch ----------------

extern "C" void kernel_launch(void* const* d_in, const int* in_sizes, int n_in,
                              void* d_out, int out_size, void* d_ws, size_t ws_size,
                              hipStream_t stream) {
    const float* x  = (const float*)d_in[0];
    const int* ei   = (const int*)d_in[1];
    const int* batch = (const int*)d_in[2];
    const float* W1 = (const float*)d_in[3];
    const float* b1 = (const float*)d_in[4];
    const float* g1 = (const float*)d_in[5];
    const float* be1 = (const float*)d_in[6];
    const float* W2 = (const float*)d_in[7];
    const float* b2 = (const float*)d_in[8];
    const float* g2 = (const float*)d_in[9];
    const float* be2 = (const float*)d_in[10];
    const float* W3 = (const float*)d_in[11];
    const float* b3 = (const float*)d_in[12];
    const float* g3 = (const float*)d_in[13];
    const float* be3 = (const float*)d_in[14];
    const float* Wl = (const float*)d_in[15];
    const float* bl = (const float*)d_in[16];
    float* out = (float*)d_out;

    char* ws = (char*)d_ws;
    size_t off = 0;
    auto alloc = [&](size_t bytes) -> char* {
        char* p = ws + off;
        off = (off + bytes + 255) & ~(size_t)255;
        return p;
    };
    float* dinv    = (float*)alloc(N_NODES * 4);
    int* offs      = (int*)alloc(N_NODES * 4);
    int* inCnt     = (int*)alloc(N_NODES * 4);
    int* cursor    = (int*)alloc(NBUCKET * 4);
    int* bcsr      = (int*)alloc((size_t)NBUCKET * SLAB * 4);
    unsigned* csrp = (unsigned*)alloc((size_t)NBUCKET * SLAB * 4);
    float* statsP  = (float*)alloc(3 * SREP * 256 * 4);
    float* sums    = (float*)alloc(NGRAPH * FDIM * 4);
    unsigned short* Wt = (unsigned short*)alloc(3 * 16384 * 2);
    unsigned short* T16 = (unsigned short*)alloc((size_t)N_NODES * FDIM * 2);  // shard-major
    unsigned* H    = (unsigned*)alloc((size_t)N_NODES * 64 * 4);

    const int nb_nodes = (N_NODES + 255) / 256;   // 391
    const int nb_gemm = (N_NODES + 63) / 64;      // 1563
    const int nb_agg = (N_NODES / 32) * NSHARD;   // 25000 (multiple of 8)
    const int nb_pool = (N_NODES + 63) / 64;      // 1563

    // preprocessing: bin -> per-bucket counting sort -> packed coef expansion
    initk<<<nb_nodes, 256, 0, stream>>>(statsP, sums, cursor);
    bink<<<NBINBLK, 256, 0, stream>>>(ei, cursor, bcsr);
    sortk<<<NBUCKET, 256, 0, stream>>>(cursor, bcsr, offs, inCnt, dinv);
    coefk<<<NBUCKET, 256, 0, stream>>>(cursor, bcsr, dinv, csrp);
    transposeW<<<24, 256, 0, stream>>>(W1, W2, W3, Wt);

    // layer 1
    gemmMF<0><<<nb_gemm, 256, 0, stream>>>(x, Wt, nullptr, nullptr, nullptr, T16);
    agg<<<nb_agg, 256, 0, stream>>>((const unsigned*)T16, csrp, offs, inCnt, dinv, b1, H, statsP);

    // layer 2 (BN1+ReLU fused into GEMM A-stage)
    gemmMF<1><<<nb_gemm, 256, 0, stream>>>(H, Wt + 16384, statsP, g1, be1, T16);
    agg<<<nb_agg, 256, 0, stream>>>((const unsigned*)T16, csrp, offs, inCnt, dinv, b2, H, statsP + SREP * 256);

    // layer 3
    gemmMF<1><<<nb_gemm, 256, 0, stream>>>(H, Wt + 32768, statsP + SREP * 256, g2, be2, T16);
    agg<<<nb_agg, 256, 0, stream>>>((const unsigned*)T16, csrp, offs, inCnt, dinv, b3, H, statsP + 2 * SREP * 256);

    // pool (BN3+ReLU fused) + linear
    poolsum<<<nb_pool, 128, 0, stream>>>(H, batch, statsP + 2 * SREP * 256, g3, be3, sums);
    finalk<<<NGRAPH, 128, 0, stream>>>(sums, batch, Wl, bl, out);
}

// Round 13
// 361.066 us; speedup vs baseline: 2.6593x; 2.0402x over previous
//
#include <hip/hip_runtime.h>
#include <hip/hip_bf16.h>

#define N_NODES 100000
#define E_EDGES 1600000
#define FDIM 128
#define NGRAPH 256
#define NPB 256            // nodes per bucket (dst >> 8)
#define NBUCKET 391        // ceil(N / 256)
#define SLAB 4800          // slab capacity (mean 4092, sigma ~64, +11 sigma)
#define BCHUNK 2048        // edges per bin block (small => parallelism)
#define NBINBLK ((E_EDGES + BCHUNK - 1) / BCHUNK)   // 782
#define LDSW 136           // padded bf16 row stride (128 + 8)
#define SREP 16            // stats replication

typedef __attribute__((ext_vector_type(8))) short bf16x8;
typedef __attribute__((ext_vector_type(4))) float f32x4;

__device__ __forceinline__ unsigned pack_bf16(float a, float b) {
    unsigned ua = __float_as_uint(a);
    unsigned ub = __float_as_uint(b);
    ua = ua + 0x7fffu + ((ua >> 16) & 1u);
    ub = ub + 0x7fffu + ((ub >> 16) & 1u);
    return (ua >> 16) | (ub & 0xffff0000u);
}
__device__ __forceinline__ unsigned short bf16_1(float a) {
    unsigned ua = __float_as_uint(a);
    ua = ua + 0x7fffu + ((ua >> 16) & 1u);
    return (unsigned short)(ua >> 16);
}
__device__ __forceinline__ float bf_lo(unsigned u) { return __uint_as_float(u << 16); }
__device__ __forceinline__ float bf_hi(unsigned u) { return __uint_as_float(u & 0xffff0000u); }

// ---------------- preprocessing ----------------

__global__ void initk(float* __restrict__ statsP, float* __restrict__ sums,
                      int* __restrict__ cursor) {
    int i = blockIdx.x * blockDim.x + threadIdx.x;
    if (i < 3 * SREP * 256) statsP[i] = 0.0f;       // replicated stats slabs
    if (i < NGRAPH * FDIM) sums[i] = 0.0f;          // pooled sums
    if (i < NBUCKET) cursor[i] = i * SLAB;          // bucket slab cursors
}

// Phase 1: bin edges by dst bucket; clustered slab writes.
__global__ __launch_bounds__(256) void bink(const int* __restrict__ ei,
                                            int* __restrict__ cursor,
                                            int* __restrict__ bcsr) {
    __shared__ int hist[NBUCKET];
    __shared__ int base[NBUCKET];
    int t = threadIdx.x;
    for (int b = t; b < NBUCKET; b += 256) hist[b] = 0;
    __syncthreads();
    int e0 = blockIdx.x * BCHUNK;
    int e1 = e0 + BCHUNK; if (e1 > E_EDGES) e1 = E_EDGES;
    for (int e = e0 + t; e < e1; e += 256) {
        atomicAdd(&hist[ei[E_EDGES + e] >> 8], 1);
    }
    __syncthreads();
    for (int b = t; b < NBUCKET; b += 256) {
        int h = hist[b];
        base[b] = h ? atomicAdd(&cursor[b], h) : 0;
        hist[b] = 0;
    }
    __syncthreads();
    for (int e = e0 + t; e < e1; e += 256) {
        int s = ei[e];
        int d = ei[E_EDGES + e];
        int bk = d >> 8;
        int lp = atomicAdd(&hist[bk], 1);
        int pos = base[bk] + lp;
        if (pos < (bk + 1) * SLAB)                    // overflow guard
            bcsr[pos] = s | ((d & 255) << 17);
    }
}

// Phase 2: per-bucket LDS counting sort -> per-node grouping (in place, keeps
// dst-local bits), per-node offsets, in-counts, and dinv.
__global__ __launch_bounds__(256) void sortk(const int* __restrict__ cursor,
                                             int* __restrict__ bcsr,
                                             int* __restrict__ offs,
                                             int* __restrict__ inCnt,
                                             float* __restrict__ dinv) {
    __shared__ int ent[SLAB];      // 19.2 KB
    __shared__ int hist[NPB];
    __shared__ int hcur[NPB];
    __shared__ int htmp[NPB];
    int t = threadIdx.x;
    int bk = blockIdx.x;
    int slab = bk * SLAB;
    int cnt = cursor[bk] - slab;
    if (cnt > SLAB) cnt = SLAB;
    hist[t] = 0;
    __syncthreads();
    for (int i = t; i < cnt; i += 256) {
        int v = bcsr[slab + i];
        ent[i] = v;
        atomicAdd(&hist[v >> 17], 1);
    }
    __syncthreads();
    int myc = hist[t];
    htmp[t] = myc;
    __syncthreads();
    for (int st = 1; st < 256; st <<= 1) {
        int x = htmp[t];
        int y = (t >= st) ? htmp[t - st] : 0;
        __syncthreads();
        htmp[t] = x + y;
        __syncthreads();
    }
    int excl = htmp[t] - myc;
    hist[t] = excl;                 // reuse as scatter base
    hcur[t] = 0;
    int gn = bk * NPB + t;
    if (gn < N_NODES) {
        inCnt[gn] = myc;
        offs[gn] = slab + excl;
        dinv[gn] = rsqrtf((float)(1 + myc));   // +1 self-loop
    }
    __syncthreads();
    for (int i = t; i < cnt; i += 256) {
        int v = ent[i];
        int dl = v >> 17;
        int lp = atomicAdd(&hcur[dl], 1);
        bcsr[slab + hist[dl] + lp] = v;        // keep dl bits for coefk
    }
}

// Phase 3: expand to (src, coef) int2 entries; sequential, dinv L2-resident.
__global__ __launch_bounds__(256) void coefk(const int* __restrict__ cursor,
                                             const int* __restrict__ bcsr,
                                             const float* __restrict__ dinv,
                                             int2* __restrict__ csr2) {
    int bk = blockIdx.x;
    int slab = bk * SLAB;
    int cnt = cursor[bk] - slab;
    if (cnt > SLAB) cnt = SLAB;
    for (int i = threadIdx.x; i < cnt; i += 256) {
        int v = bcsr[slab + i];
        int s = v & 0x1FFFF;
        int d = bk * NPB + (v >> 17);
        csr2[slab + i] = make_int2(s, __float_as_int(dinv[s] * dinv[d]));
    }
}

// W^T (bf16) precompute: Wt[widx][n][k] = bf16(W[k][n])
__global__ __launch_bounds__(256) void transposeW(const float* __restrict__ W1,
                                                  const float* __restrict__ W2,
                                                  const float* __restrict__ W3,
                                                  unsigned short* __restrict__ Wt) {
    int b = blockIdx.x;
    int widx = b >> 3;
    int n0 = (b & 7) * 16;
    const float* W = (widx == 0) ? W1 : (widx == 1) ? W2 : W3;
    unsigned short* dst = Wt + widx * 16384;
    int t = threadIdx.x;
    int n = n0 + (t & 15);
#pragma unroll
    for (int i = 0; i < 8; i++) {
        int k = (t >> 4) + i * 16;
        dst[n * 128 + k] = bf16_1(W[k * 128 + n]);
    }
}

// ---------------- MFMA GEMM: T_bf16[N,128] = act(A[N,128]) @ W ----------------
// MODE 0: A fp32, no BN (layer 1). MODE 1: A bf16 (uint-packed), BN+ReLU fused.

template <int MODE>
__global__ __launch_bounds__(256, 2) void gemmMF(const void* __restrict__ Ain,
                                                 const unsigned short* __restrict__ Wt,
                                                 const float* __restrict__ statsP,
                                                 const float* __restrict__ g,
                                                 const float* __restrict__ be,
                                                 unsigned short* __restrict__ outT) {
    __shared__ unsigned short sA[64 * LDSW];
    __shared__ unsigned short sW[128 * LDSW];
    __shared__ float sScale[FDIM], sBias[FDIM];
    int tid = threadIdx.x;
    if (MODE == 1) {
        if (tid < FDIM) {
            float s = 0.f, q = 0.f;
#pragma unroll
            for (int r = 0; r < SREP; r++) {
                s += statsP[r * 256 + tid];
                q += statsP[r * 256 + 128 + tid];
            }
            float mean = s * (1.0f / N_NODES);
            float var = q * (1.0f / N_NODES) - mean * mean;
            float sc = g[tid] * rsqrtf(var + 1e-5f);
            sScale[tid] = sc;
            sBias[tid] = be[tid] - mean * sc;
        }
        __syncthreads();
    }
    int row0 = blockIdx.x * 64;
    {
        const uint4* Wt4 = (const uint4*)Wt;
#pragma unroll
        for (int i = 0; i < 8; i++) {
            int flat = tid + 256 * i;        // 0..2047
            int r = flat >> 4, c8 = flat & 15;
            uint4 v = Wt4[flat];
            *(uint4*)&sW[r * LDSW + c8 * 8] = v;
        }
    }
    if (MODE == 0) {
        const float4* A4 = (const float4*)Ain;
#pragma unroll
        for (int i = 0; i < 8; i++) {
            int flat = tid + 256 * i;        // 0..2047
            int r = flat >> 5, c4 = flat & 31;
            int grow = row0 + r;
            float4 v = make_float4(0.f, 0.f, 0.f, 0.f);
            if (grow < N_NODES) v = A4[grow * 32 + c4];
            uint2 p;
            p.x = pack_bf16(v.x, v.y);
            p.y = pack_bf16(v.z, v.w);
            *(uint2*)&sA[r * LDSW + c4 * 4] = p;
        }
    } else {
        const uint2* A2 = (const uint2*)Ain;
#pragma unroll
        for (int i = 0; i < 8; i++) {
            int flat = tid + 256 * i;        // 0..2047
            int r = flat >> 5, c4 = flat & 31;
            int grow = row0 + r;
            uint2 u = make_uint2(0u, 0u);
            if (grow < N_NODES) u = A2[grow * 32 + c4];
            int ch = c4 * 4;
            float vx = fmaxf(bf_lo(u.x) * sScale[ch + 0] + sBias[ch + 0], 0.f);
            float vy = fmaxf(bf_hi(u.x) * sScale[ch + 1] + sBias[ch + 1], 0.f);
            float vz = fmaxf(bf_lo(u.y) * sScale[ch + 2] + sBias[ch + 2], 0.f);
            float vw = fmaxf(bf_hi(u.y) * sScale[ch + 3] + sBias[ch + 3], 0.f);
            uint2 p;
            p.x = pack_bf16(vx, vy);
            p.y = pack_bf16(vz, vw);
            *(uint2*)&sA[r * LDSW + c4 * 4] = p;
        }
    }
    __syncthreads();

    int lane = tid & 63;
    int w = tid >> 6;         // wave id: cols w*32..w*32+31
    int rbase = lane & 15;
    int kgrp = lane >> 4;     // 0..3
    f32x4 acc[4][2];
#pragma unroll
    for (int mf = 0; mf < 4; mf++)
#pragma unroll
        for (int nf = 0; nf < 2; nf++) acc[mf][nf] = (f32x4){0.f, 0.f, 0.f, 0.f};

#pragma unroll
    for (int kk = 0; kk < 4; kk++) {
        int kb = kk * 32 + kgrp * 8;
        bf16x8 af[4], bfr[2];
#pragma unroll
        for (int mf = 0; mf < 4; mf++)
            af[mf] = *(const bf16x8*)&sA[(mf * 16 + rbase) * LDSW + kb];
#pragma unroll
        for (int nf = 0; nf < 2; nf++)
            bfr[nf] = *(const bf16x8*)&sW[(w * 32 + nf * 16 + rbase) * LDSW + kb];
#pragma unroll
        for (int mf = 0; mf < 4; mf++)
#pragma unroll
            for (int nf = 0; nf < 2; nf++)
                acc[mf][nf] = __builtin_amdgcn_mfma_f32_16x16x32_bf16(
                    af[mf], bfr[nf], acc[mf][nf], 0, 0, 0);
    }
#pragma unroll
    for (int mf = 0; mf < 4; mf++) {
#pragma unroll
        for (int nf = 0; nf < 2; nf++) {
            int col = w * 32 + nf * 16 + rbase;
#pragma unroll
            for (int j = 0; j < 4; j++) {
                int grow = row0 + mf * 16 + kgrp * 4 + j;
                if (grow < N_NODES) {
                    outT[(size_t)grow * FDIM + col] = bf16_1(acc[mf][nf][j]);
                }
            }
        }
    }
}

// ---------------- edge aggregation (gather form, unroll-16) + fused BN stats --
// 3125 blocks x 4 waves x 8 nodes; lane = channel-pair; bf16 in/out.
// CSR entry reads are wave-uniform -> scalar loads. 16 row-gathers in flight.

__global__ __launch_bounds__(256) void agg(const unsigned* __restrict__ t,
                                           const int2* __restrict__ csr2,
                                           const int* __restrict__ offs,
                                           const int* __restrict__ inCnt,
                                           const float* __restrict__ dinv,
                                           const float* __restrict__ bias,
                                           unsigned* __restrict__ outH,
                                           float* __restrict__ statsP) {
    int tid = threadIdx.x;
    int lane = tid & 63;
    int wid = tid >> 6;
    const float2* bias2 = (const float2*)bias;
    float2 b = bias2[lane];
    float s0 = 0.f, s1 = 0.f, q0 = 0.f, q1 = 0.f;
    for (int it = 0; it < 8; it++) {
        int node = __builtin_amdgcn_readfirstlane(blockIdx.x * 32 + wid * 8 + it);
        float di = dinv[node];
        unsigned su = t[node * 64 + lane];
        float cs = di * di;
        float a0 = bf_lo(su) * cs;
        float a1 = bf_hi(su) * cs;
        int start = offs[node];
        int cnt = inCnt[node];
        int e = 0;
        for (; e + 16 <= cnt; e += 16) {
            int2 E[16];
            unsigned U[16];
#pragma unroll
            for (int k = 0; k < 16; k++) E[k] = csr2[start + e + k];
#pragma unroll
            for (int k = 0; k < 16; k++) U[k] = t[E[k].x * 64 + lane];
#pragma unroll
            for (int k = 0; k < 16; k++) {
                float f = __int_as_float(E[k].y);
                a0 += f * bf_lo(U[k]);
                a1 += f * bf_hi(U[k]);
            }
        }
        for (; e + 4 <= cnt; e += 4) {
            int2 E0 = csr2[start + e + 0];
            int2 E1 = csr2[start + e + 1];
            int2 E2 = csr2[start + e + 2];
            int2 E3 = csr2[start + e + 3];
            unsigned u0 = t[E0.x * 64 + lane];
            unsigned u1 = t[E1.x * 64 + lane];
            unsigned u2 = t[E2.x * 64 + lane];
            unsigned u3 = t[E3.x * 64 + lane];
            float f0 = __int_as_float(E0.y);
            float f1 = __int_as_float(E1.y);
            float f2 = __int_as_float(E2.y);
            float f3 = __int_as_float(E3.y);
            a0 += f0 * bf_lo(u0); a1 += f0 * bf_hi(u0);
            a0 += f1 * bf_lo(u1); a1 += f1 * bf_hi(u1);
            a0 += f2 * bf_lo(u2); a1 += f2 * bf_hi(u2);
            a0 += f3 * bf_lo(u3); a1 += f3 * bf_hi(u3);
        }
        for (; e < cnt; e++) {
            int2 E = csr2[start + e];
            float cf = __int_as_float(E.y);
            unsigned u = t[E.x * 64 + lane];
            a0 += cf * bf_lo(u);
            a1 += cf * bf_hi(u);
        }
        a0 += b.x;
        a1 += b.y;
        outH[node * 64 + lane] = pack_bf16(a0, a1);
        s0 += a0; q0 += a0 * a0;
        s1 += a1; q1 += a1 * a1;
    }
    __shared__ float rS0[256], rS1[256], rQ0[256], rQ1[256];
    rS0[tid] = s0; rS1[tid] = s1; rQ0[tid] = q0; rQ1[tid] = q1;
    __syncthreads();
    if (tid < 64) {
        float S0 = 0.f, S1 = 0.f, Q0 = 0.f, Q1 = 0.f;
#pragma unroll
        for (int w = 0; w < 4; w++) {
            S0 += rS0[w * 64 + tid];
            S1 += rS1[w * 64 + tid];
            Q0 += rQ0[w * 64 + tid];
            Q1 += rQ1[w * 64 + tid];
        }
        float* p = statsP + (blockIdx.x & (SREP - 1)) * 256;
        atomicAdd(&p[2 * tid + 0], S0);
        atomicAdd(&p[2 * tid + 1], S1);
        atomicAdd(&p[128 + 2 * tid + 0], Q0);
        atomicAdd(&p[128 + 2 * tid + 1], Q1);
    }
}

// ---------------- pool phase 1: BN3+ReLU + segment-sum (bf16 H) ----------------

__global__ __launch_bounds__(128) void poolsum(const unsigned* __restrict__ h,
                                               const int* __restrict__ batch,
                                               const float* __restrict__ statsP,
                                               const float* __restrict__ g3,
                                               const float* __restrict__ be3,
                                               float* __restrict__ sums) {
    int c = threadIdx.x;
    int base = blockIdx.x * 64;
    float s = 0.f, q = 0.f;
#pragma unroll
    for (int r = 0; r < SREP; r++) {
        s += statsP[r * 256 + c];
        q += statsP[r * 256 + 128 + c];
    }
    float mean = s * (1.0f / N_NODES);
    float var = q * (1.0f / N_NODES) - mean * mean;
    float sc = g3[c] * rsqrtf(var + 1e-5f);
    float bi = be3[c] - mean * sc;
    __shared__ int sb[64];
    if (c < 64) {
        int idx = base + c;
        sb[c] = (idx < N_NODES) ? batch[idx] : -1;
    }
    __syncthreads();
    float acc = 0.f;
    int gcur = sb[0];
    int half = c & 1;
    int cu = c >> 1;
    for (int r = 0; r < 64; r++) {
        int idx = base + r;
        if (idx >= N_NODES) break;
        int gr = sb[r];
        if (gr != gcur) {
            atomicAdd(&sums[gcur * FDIM + c], acc);
            acc = 0.f;
            gcur = gr;
        }
        unsigned u = h[(size_t)idx * 64 + cu];
        float v = half ? bf_hi(u) : bf_lo(u);
        acc += fmaxf(v * sc + bi, 0.f);
    }
    atomicAdd(&sums[gcur * FDIM + c], acc);
}

// ---------------- pool phase 2: divide + final linear ----------------

__global__ __launch_bounds__(128) void finalk(const float* __restrict__ sums,
                                              const int* __restrict__ batch,
                                              const float* __restrict__ Wl,
                                              const float* __restrict__ bl,
                                              float* __restrict__ out) {
    int g = blockIdx.x;
    int c = threadIdx.x;
    int lo = 0, hi = N_NODES;
    while (lo < hi) { int m = (lo + hi) >> 1; if (batch[m] < g) lo = m + 1; else hi = m; }
    int start = lo;
    lo = start; hi = N_NODES;
    while (lo < hi) { int m = (lo + hi) >> 1; if (batch[m] < g + 1) lo = m + 1; else hi = m; }
    int cnt = lo - start;
    float v = sums[g * FDIM + c] / fmaxf((float)cnt, 1.0f) * Wl[c];
    __shared__ float red[FDIM];
    red[c] = v;
    __syncthreads();
    for (int st = 64; st > 0; st >>= 1) {
        if (c < st) red[c] += red[c + st];
        __syncthreads();
    }
    if (c == 0) out[g] = red[0] + bl[0];
}

// ---------------- launch ----------------

extern "C" void kernel_launch(void* const* d_in, const int* in_sizes, int n_in,
                              void* d_out, int out_size, void* d_ws, size_t ws_size,
                              hipStream_t stream) {
    const float* x  = (const float*)d_in[0];
    const int* ei   = (const int*)d_in[1];
    const int* batch = (const int*)d_in[2];
    const float* W1 = (const float*)d_in[3];
    const float* b1 = (const float*)d_in[4];
    const float* g1 = (const float*)d_in[5];
    const float* be1 = (const float*)d_in[6];
    const float* W2 = (const float*)d_in[7];
    const float* b2 = (const float*)d_in[8];
    const float* g2 = (const float*)d_in[9];
    const float* be2 = (const float*)d_in[10];
    const float* W3 = (const float*)d_in[11];
    const float* b3 = (const float*)d_in[12];
    const float* g3 = (const float*)d_in[13];
    const float* be3 = (const float*)d_in[14];
    const float* Wl = (const float*)d_in[15];
    const float* bl = (const float*)d_in[16];
    float* out = (float*)d_out;

    char* ws = (char*)d_ws;
    size_t off = 0;
    auto alloc = [&](size_t bytes) -> char* {
        char* p = ws + off;
        off = (off + bytes + 255) & ~(size_t)255;
        return p;
    };
    float* dinv    = (float*)alloc(N_NODES * 4);
    int* offs      = (int*)alloc(N_NODES * 4);
    int* inCnt     = (int*)alloc(N_NODES * 4);
    int* cursor    = (int*)alloc(NBUCKET * 4);
    int* bcsr      = (int*)alloc((size_t)NBUCKET * SLAB * 4);
    int2* csr2     = (int2*)alloc((size_t)NBUCKET * SLAB * 8);
    float* statsP  = (float*)alloc(3 * SREP * 256 * 4);
    float* sums    = (float*)alloc(NGRAPH * FDIM * 4);
    unsigned short* Wt = (unsigned short*)alloc(3 * 16384 * 2);
    unsigned short* T16 = (unsigned short*)alloc((size_t)N_NODES * FDIM * 2);
    unsigned* H    = (unsigned*)alloc((size_t)N_NODES * 64 * 4);

    const int nb_nodes = (N_NODES + 255) / 256;   // 391
    const int nb_gemm = (N_NODES + 63) / 64;      // 1563
    const int nb_agg = N_NODES / 32;              // 3125
    const int nb_pool = (N_NODES + 63) / 64;      // 1563

    // preprocessing: bin -> per-bucket counting sort -> coef expansion
    initk<<<nb_nodes, 256, 0, stream>>>(statsP, sums, cursor);
    bink<<<NBINBLK, 256, 0, stream>>>(ei, cursor, bcsr);
    sortk<<<NBUCKET, 256, 0, stream>>>(cursor, bcsr, offs, inCnt, dinv);
    coefk<<<NBUCKET, 256, 0, stream>>>(cursor, bcsr, dinv, csr2);
    transposeW<<<24, 256, 0, stream>>>(W1, W2, W3, Wt);

    // layer 1
    gemmMF<0><<<nb_gemm, 256, 0, stream>>>(x, Wt, nullptr, nullptr, nullptr, T16);
    agg<<<nb_agg, 256, 0, stream>>>((const unsigned*)T16, csr2, offs, inCnt, dinv, b1, H, statsP);

    // layer 2 (BN1+ReLU fused into GEMM A-stage)
    gemmMF<1><<<nb_gemm, 256, 0, stream>>>(H, Wt + 16384, statsP, g1, be1, T16);
    agg<<<nb_agg, 256, 0, stream>>>((const unsigned*)T16, csr2, offs, inCnt, dinv, b2, H, statsP + SREP * 256);

    // layer 3
    gemmMF<1><<<nb_gemm, 256, 0, stream>>>(H, Wt + 32768, statsP + SREP * 256, g2, be2, T16);
    agg<<<nb_agg, 256, 0, stream>>>((const unsigned*)T16, csr2, offs, inCnt, dinv, b3, H, statsP + 2 * SREP * 256);

    // pool (BN3+ReLU fused) + linear
    poolsum<<<nb_pool, 128, 0, stream>>>(H, batch, statsP + 2 * SREP * 256, g3, be3, sums);
    finalk<<<NGRAPH, 128, 0, stream>>>(sums, batch, Wl, bl, out);
}